// Round 4
// baseline (193.811 us; speedup 1.0000x reference)
//
#include <hip/hip_runtime.h>
#include <hip/hip_bf16.h>

// FlowNetC correlation: B=4, C=256, H=W=96, PAD=MAX_DISP=20, STRIDE2=2, D=21.
// out[b, oy*21+ox, h, w] = (1/C) * sum_c x1[b,c,h,w] * x2[b,c,h+2oy-20,w+2ox-20]
//
// dx even -> split w by parity. Per (b,h,oy,par): out[i,ox] = sum_c A[c,i]*B[c,j],
// j = i+ox-10, i=w>>1 in [0,48). Band GEMM, MFMA 16x16x32 bf16, tiles (mt,u):
// i-tile mt in {0,1,2}, j-tile u in {0,1,2}; 7 valid pairs.
//
// R4 structure: ZERO barriers in corr_kernel.
//  - u-major wave assignment: wave owns one u (one B row-set) and <=2 mt.
//    A fragments register-resident across the 7-oy loop; B fragments loaded
//    directly from global (L2) each oy (8 x b128 per wave) - no LDS staging.
//  - Epilogue transpose through a PRIVATE per-wave LDS slab (intra-wave
//    lgkmcnt ordering only, no __syncthreads). Store descriptors (global
//    offset + ownership bit31 + j-in-range bit30) precomputed, oy-invariant.
//  - Branchless h2 handling: clamp + scale=0 keeps the oy loop straight-line.
// Wave partition per par: wv0:(u0,mt{0,1}) wv1:(u1,mt{0,1}) wv2:(u1,mt{2})
// wv3:(u2,mt{1,2}). Ownership at store: u_own(j) = clamp(j>>4, 0, 2); every
// (i,ox) has a unique owner wave, fringe (j<0 or j>=48) stores 0.

typedef __bf16 bf16x8 __attribute__((ext_vector_type(8)));
typedef float f32x4 __attribute__((ext_vector_type(4)));

#define B_ 4
#define C_ 256
#define H_ 96
#define W_ 96
#define NOFF 21
#define IMG_ELEMS (96 * C_)             // rows(2par*48) * 256 halfs = 48KB
#define X1T_ELEMS (B_ * H_ * IMG_ELEMS) // 9,437,184 halfs

__device__ __forceinline__ unsigned short f32_to_bf16_rne(float f) {
    union { float f; unsigned u; } v; v.f = f;
    unsigned u = v.u;
    return (unsigned short)((u + 0x7fffu + ((u >> 16) & 1u)) >> 16);
}

// ---------------------------------------------------------------------------
// Prep: fp32 NCHW -> bf16 transposed [b][h][row][c], row = par*48 + (w>>1).
// One block per (b,h,src,c-block-of-64). Linear layout (no swizzle needed:
// consumers read from global, not LDS).
// ---------------------------------------------------------------------------
__global__ __launch_bounds__(256) void prep_kernel(const float* __restrict__ x1,
                                                   const float* __restrict__ x2,
                                                   unsigned short* __restrict__ ws) {
    __shared__ float tile[96 * 65];   // [w][c_local], pitch 65: conflict-free
    int bid = blockIdx.x;
    int cblk  = bid & 3;
    int which = (bid >> 2) & 1;
    int bh    = bid >> 3;             // 0..383
    int h = bh % H_;
    int b = bh / H_;
    int c0 = cblk << 6;

    const float* src = (which ? x2 : x1) + ((size_t)(b * C_ + c0) * H_ + h) * W_;
    unsigned short* dst = ws + (size_t)which * X1T_ELEMS + (size_t)(b * H_ + h) * IMG_ELEMS;

    for (int idx = threadIdx.x; idx < 64 * 96; idx += 256) {
        int c = idx / 96, w = idx - c * 96;
        tile[w * 65 + c] = src[c * (H_ * W_) + w];
    }
    __syncthreads();

    for (int idx = threadIdx.x; idx < 96 * 8; idx += 256) {
        int row = idx >> 3, tp = idx & 7;
        int par = row / 48, i = row - par * 48;
        int w = 2 * i + par;
        const float* fsrc = &tile[w * 65 + (tp << 3)];
        unsigned pk[4];
#pragma unroll
        for (int e = 0; e < 4; ++e) {
            unsigned lo = f32_to_bf16_rne(fsrc[2 * e]);
            unsigned hi = f32_to_bf16_rne(fsrc[2 * e + 1]);
            pk[e] = lo | (hi << 16);
        }
        *(uint4*)(dst + (size_t)row * C_ + c0 + (tp << 3)) =
            make_uint4(pk[0], pk[1], pk[2], pk[3]);
    }
}

// ---------------------------------------------------------------------------
// Main: 2304 blocks x 256 threads (4 waves). Block = (b, h, og, par).
// ---------------------------------------------------------------------------
__global__ __launch_bounds__(256, 3) void corr_kernel(const unsigned short* __restrict__ ws,
                                                      float* __restrict__ out) {
    __shared__ float slab[3264];       // 4 waves x (2 planes x 21 x pitch19) + slack

    int bid = blockIdx.x;
    int xcd = bid & 7, rest = bid >> 3;           // XCD-major: (b, h-half) per XCD
    int b  = xcd >> 1;
    int h  = ((xcd & 1) ? 48 : 0) + rest / 6;
    int sub = rest % 6;
    int og = sub >> 1, par = sub & 1;

    int tid = threadIdx.x;
    int wv = tid >> 6, lane = tid & 63;
    int n = lane & 15, q = lane >> 4;

    const int utab[4]  = {0, 1, 1, 2};
    const int mtbt[4]  = {0, 0, 2, 1};
    const int nmtt[4]  = {2, 2, 1, 2};
    int u = utab[wv], mtb = mtbt[wv], nmt = nmtt[wv];

    const unsigned short* ws1 = ws;
    const unsigned short* ws2 = ws + X1T_ELEMS;

    // ---- A fragments: register-resident for the whole oy loop ----
    bf16x8 afrag[2][8];
#pragma unroll
    for (int mtl = 0; mtl < 2; ++mtl) {
        if (mtl < nmt) {
            int rowA = par * 48 + 16 * (mtb + mtl) + n;
            const unsigned short* Ab = ws1 + (size_t)(b * H_ + h) * IMG_ELEMS
                                           + rowA * C_ + q * 8;
#pragma unroll
            for (int ks = 0; ks < 8; ++ks)
                afrag[mtl][ks] = *(const bf16x8*)(Ab + ks * 32);
        }
    }

    // ---- oy-invariant precompute ----
    int rowB = par * 48 + 16 * u + n;
    const unsigned short* Bbase0 = ws2 + (size_t)(b * H_) * IMG_ELEMS + rowB * C_ + q * 8;

    int ox00 = 16 * u - 16 * mtb + n - 4 * q + 10;     // ox at (mtl=0, r=0)
    int scb2 = wv * 800 + 19 * ox00 + 4 * q;           // slab scatter base

    // Readback descriptors: e = ox*9216 + 2*i + par | own<<31 | jin<<30
    int ek[11];
#pragma unroll
    for (int k = 0; k < 11; ++k) {
        int f = k * 64 + lane;
        int m = f & 15, g = f >> 4;
        int mtl = (g >= 21) ? 1 : 0;
        int ox = g - 21 * mtl;
        int live = (f < nmt * 336) && (mtl < nmt) && (ox < 21);
        int i = 16 * (mtb + mtl) + m;
        int j = i + ox - 10;
        int uo = (j < 0) ? 0 : ((j >= 48) ? 2 : (j >> 4));
        int e = ox * 9216 + 2 * i + par;
        if (j >= 0 && j < 48) e |= 0x40000000;
        if (live && uo == u)  e |= 0x80000000u;
        ek[k] = e;
    }
    int sb = wv * 800 + lane + 3 * (lane >> 4);        // slab readback base (+76k)

    int oy0 = og * 7;
    float* op0 = out + (size_t)((b * 441 + oy0 * NOFF) * H_ + h) * W_;

    // ---- 7-oy loop: straight-line, barrier-free ----
    for (int t = 0; t < 7; ++t) {
        int oy = oy0 + t;
        int h2 = h + 2 * oy - 20;
        int valid = ((unsigned)h2 < 96u);
        int h2c = valid ? h2 : 0;
        float scalef = valid ? (1.0f / 256.0f) : 0.0f;

        // B fragments straight from global (L2-resident packed image)
        const unsigned short* Bb = Bbase0 + (size_t)h2c * IMG_ELEMS;
        bf16x8 bf[8];
#pragma unroll
        for (int ks = 0; ks < 8; ++ks)
            bf[ks] = *(const bf16x8*)(Bb + ks * 32);

        f32x4 acc0 = {0.f, 0.f, 0.f, 0.f};
        f32x4 acc1 = {0.f, 0.f, 0.f, 0.f};
        if (nmt > 1) {
#pragma unroll
            for (int ks = 0; ks < 8; ++ks) {
                acc0 = __builtin_amdgcn_mfma_f32_16x16x32_bf16(afrag[0][ks], bf[ks], acc0, 0, 0, 0);
                acc1 = __builtin_amdgcn_mfma_f32_16x16x32_bf16(afrag[1][ks], bf[ks], acc1, 0, 0, 0);
            }
        } else {
#pragma unroll
            for (int ks = 0; ks < 8; ++ks)
                acc0 = __builtin_amdgcn_mfma_f32_16x16x32_bf16(afrag[0][ks], bf[ks], acc0, 0, 0, 0);
        }

        // Scatter into private slab (intra-wave only; masked by ox range)
#pragma unroll
        for (int r = 0; r < 4; ++r) {
            if ((unsigned)(ox00 - r) < 21u)
                slab[scb2 - 18 * r] = acc0[r];
            if (nmt > 1 && (unsigned)(ox00 - 16 - r) < 21u)
                slab[scb2 + 95 - 18 * r] = acc1[r];
        }

        // Readback + store (stride-8B runs; par-sibling block fills the gaps)
        float* op = op0 + t * (NOFF * H_ * W_);
#pragma unroll
        for (int k = 0; k < 11; ++k) {
            int e = ek[k];
            float v = slab[sb + 76 * k];
            float val = (e & 0x40000000) ? v * scalef : 0.0f;
            if (e < 0)
                op[e & 0x0FFFFFFF] = val;
        }
    }
}

// ---------------------------------------------------------------------------
// Fallback (ws too small): direct fp32, slow but correct.
// ---------------------------------------------------------------------------
__global__ __launch_bounds__(256) void corr_fallback(const float* __restrict__ x1,
                                                     const float* __restrict__ x2,
                                                     float* __restrict__ out) {
    int bid = blockIdx.x;
    int oy = bid % NOFF, h = (bid / NOFF) % H_, b = bid / (NOFF * H_);
    int dy = 2 * oy - 20, h2 = h + dy;
    int outbase = ((b * 441 + oy * NOFF) * H_ + h) * W_;
    for (int idx = threadIdx.x; idx < NOFF * W_; idx += 256) {
        int ox = idx / W_, w = idx % W_;
        float acc = 0.f;
        int w2 = w + 2 * ox - 20;
        if (h2 >= 0 && h2 < H_ && w2 >= 0 && w2 < W_) {
            const float* p1 = x1 + (size_t)b * C_ * H_ * W_ + h * W_ + w;
            const float* p2 = x2 + (size_t)b * C_ * H_ * W_ + h2 * W_ + w2;
            for (int c = 0; c < C_; ++c) acc += p1[c * (H_ * W_)] * p2[c * (H_ * W_)];
        }
        out[outbase + ox * (H_ * W_) + w] = acc * (1.0f / 256.0f);
    }
}

extern "C" void kernel_launch(void* const* d_in, const int* in_sizes, int n_in,
                              void* d_out, int out_size, void* d_ws, size_t ws_size,
                              hipStream_t stream) {
    const float* x1 = (const float*)d_in[0];
    const float* x2 = (const float*)d_in[1];
    float* out = (float*)d_out;

    size_t need = (size_t)2 * X1T_ELEMS * sizeof(unsigned short);  // 37.7 MB
    if (ws_size >= need) {
        unsigned short* ws = (unsigned short*)d_ws;
        prep_kernel<<<B_ * H_ * 2 * 4, 256, 0, stream>>>(x1, x2, ws);
        corr_kernel<<<2304, 256, 0, stream>>>(ws, out);
    } else {
        corr_fallback<<<B_ * H_ * NOFF, 256, 0, stream>>>(x1, x2, out);
    }
}